// Round 6
// baseline (85.878 us; speedup 1.0000x reference)
//
#include <hip/hip_runtime.h>
#include <math.h>

#define B 512
#define DG 1024
#define P 1024
#define DA 256
#define LDP 68
#define BP (B * P)
#define BD (B * DA)

// ---------------------------------------------------------------- reductions
__device__ __forceinline__ float block_reduce_sum(float v, volatile float* red) {
    #pragma unroll
    for (int off = 32; off > 0; off >>= 1) v += __shfl_down(v, off, 64);
    const int lane = threadIdx.x & 63, wid = threadIdx.x >> 6;
    __syncthreads();
    if (lane == 0) red[wid] = v;
    __syncthreads();
    return red[0] + red[1] + red[2] + red[3];
}

__device__ __forceinline__ float wsum(float v) {
    #pragma unroll
    for (int m = 32; m > 0; m >>= 1) v += __shfl_xor(v, m, 64);
    return v;
}

#define FMA16(a4, b4, acc)                                   \
    acc[0][0] = fmaf(a4.x, b4.x, acc[0][0]);                 \
    acc[0][1] = fmaf(a4.x, b4.y, acc[0][1]);                 \
    acc[0][2] = fmaf(a4.x, b4.z, acc[0][2]);                 \
    acc[0][3] = fmaf(a4.x, b4.w, acc[0][3]);                 \
    acc[1][0] = fmaf(a4.y, b4.x, acc[1][0]);                 \
    acc[1][1] = fmaf(a4.y, b4.y, acc[1][1]);                 \
    acc[1][2] = fmaf(a4.y, b4.z, acc[1][2]);                 \
    acc[1][3] = fmaf(a4.y, b4.w, acc[1][3]);                 \
    acc[2][0] = fmaf(a4.z, b4.x, acc[2][0]);                 \
    acc[2][1] = fmaf(a4.z, b4.y, acc[2][1]);                 \
    acc[2][2] = fmaf(a4.z, b4.z, acc[2][2]);                 \
    acc[2][3] = fmaf(a4.z, b4.w, acc[2][3]);                 \
    acc[3][0] = fmaf(a4.w, b4.x, acc[3][0]);                 \
    acc[3][1] = fmaf(a4.w, b4.y, acc[3][1]);                 \
    acc[3][2] = fmaf(a4.w, b4.z, acc[3][2]);                 \
    acc[3][3] = fmaf(a4.w, b4.w, acc[3][3]);

// ---------------------------------------------------------------- staging helpers
// transpose-stage: src row-major [M][ldk], 64 rows at m0, 32 cols at k0 -> sD[k][m]
__device__ __forceinline__ void stage_T(const float* __restrict__ src, int ldk, int m0, int k0,
                                        int tid, float* sD) {
    const int m = tid >> 3, k4 = (tid & 7) * 4;
    #pragma unroll
    for (int pass = 0; pass < 2; ++pass) {
        int mm = m + pass * 32;
        float4 v = *reinterpret_cast<const float4*>(&src[(m0 + mm) * ldk + k0 + k4]);
        sD[(k4 + 0) * LDP + mm] = v.x; sD[(k4 + 1) * LDP + mm] = v.y;
        sD[(k4 + 2) * LDP + mm] = v.z; sD[(k4 + 3) * LDP + mm] = v.w;
    }
}
// transpose-stage summing 4 split-K partials (partials spaced by pstride)
__device__ __forceinline__ void stage_T4(const float* __restrict__ src, int pstride, int ldk,
                                         int m0, int k0, int tid, float* sD) {
    const int m = tid >> 3, k4 = (tid & 7) * 4;
    #pragma unroll
    for (int pass = 0; pass < 2; ++pass) {
        int mm = m + pass * 32;
        const float* base = &src[(m0 + mm) * ldk + k0 + k4];
        float4 v = *reinterpret_cast<const float4*>(base);
        #pragma unroll
        for (int s = 1; s < 4; ++s) {
            float4 w = *reinterpret_cast<const float4*>(base + s * pstride);
            v.x += w.x; v.y += w.y; v.z += w.z; v.w += w.w;
        }
        sD[(k4 + 0) * LDP + mm] = v.x; sD[(k4 + 1) * LDP + mm] = v.y;
        sD[(k4 + 2) * LDP + mm] = v.z; sD[(k4 + 3) * LDP + mm] = v.w;
    }
}
// natural-stage: src row-major [K][ldn], 32 rows at k0, 64 cols at n0 -> sD[k][n]
__device__ __forceinline__ void stage_N1(const float* __restrict__ src, int ldn, int k0, int n0,
                                         int tid, float* sD) {
    const int k = tid >> 4, n4 = (tid & 15) * 4;
    #pragma unroll
    for (int pass = 0; pass < 2; ++pass) {
        int kk = k + pass * 16;
        *reinterpret_cast<float4*>(&sD[kk * LDP + n4]) =
            *reinterpret_cast<const float4*>(&src[(k0 + kk) * ldn + n0 + n4]);
    }
}
// natural-stage summing 4 split-K partials
__device__ __forceinline__ void stage_N4(const float* __restrict__ src, int pstride, int ldn,
                                         int k0, int n0, int tid, float* sD) {
    const int k = tid >> 4, n4 = (tid & 15) * 4;
    #pragma unroll
    for (int pass = 0; pass < 2; ++pass) {
        int kk = k + pass * 16;
        const float* base = &src[(k0 + kk) * ldn + n0 + n4];
        float4 v = *reinterpret_cast<const float4*>(base);
        #pragma unroll
        for (int s = 1; s < 4; ++s) {
            float4 w = *reinterpret_cast<const float4*>(base + s * pstride);
            v.x += w.x; v.y += w.y; v.z += w.z; v.w += w.w;
        }
        *reinterpret_cast<float4*>(&sD[kk * LDP + n4]) = v;
    }
}
__device__ __forceinline__ void mm_inner(const float* sA, const float* sB, int tid, float acc[4][4]) {
    const int ty4 = (tid >> 4) * 4, tx4 = (tid & 15) * 4;
    #pragma unroll
    for (int kk = 0; kk < 32; ++kk) {
        float4 a4 = *reinterpret_cast<const float4*>(&sA[kk * LDP + ty4]);
        float4 b4 = *reinterpret_cast<const float4*>(&sB[kk * LDP + tx4]);
        FMA16(a4, b4, acc)
    }
}

// ---------------------------------------------------------------- KA:
//  t in [0,512)    : k1 - qp[ks] = hg@Wq^T partial, 64x64 tile, KS=16 (chunk 64)
//  t in [512,576)  : H  - Hp[ks][f][d] = sum_e Uq[e,f]*Vk[e,d]*gk[d], KS=4 (chunk 64)
//  t == 576        : vec4 chained matvecs
//  t in [577,833)  : per-p LN stats, one wave per p
__global__ __launch_bounds__(256) void KA(const float* __restrict__ hg, const float* __restrict__ Wq,
                                          const float* __restrict__ Uq, const float* __restrict__ Vk,
                                          const float* __restrict__ Ek, const float* __restrict__ Ev,
                                          const float* __restrict__ wk, const float* __restrict__ bk,
                                          const float* __restrict__ wv, const float* __restrict__ bv,
                                          const float* __restrict__ gk, const float* __restrict__ bkln,
                                          float* __restrict__ qp, float* __restrict__ Hp,
                                          float* __restrict__ pst, float* __restrict__ scal4,
                                          float* __restrict__ vec4) {
    __shared__ __align__(16) float sA[32 * LDP];
    __shared__ __align__(16) float sB[32 * LDP];
    const int tid = threadIdx.x;
    const int t = blockIdx.x;
    const int ty4 = (tid >> 4) * 4, tx4 = (tid & 15) * 4;

    if (t < 512) {
        const int mt = t & 7, nt = (t >> 3) & 3, ks = t >> 5;
        const int b0 = mt * 64, d0 = nt * 64, kc = ks * 64;
        float acc[4][4] = {};
        for (int kt = 0; kt < 64; kt += 32) {
            stage_T(hg, DG, b0, kc + kt, tid, sA);
            stage_T(Wq, DG, d0, kc + kt, tid, sB);
            __syncthreads();
            mm_inner(sA, sB, tid, acc);
            __syncthreads();
        }
        float* outp = qp + ks * BD;
        #pragma unroll
        for (int i = 0; i < 4; ++i) {
            float4 o = make_float4(acc[i][0], acc[i][1], acc[i][2], acc[i][3]);
            *reinterpret_cast<float4*>(&outp[(b0 + ty4 + i) * DA + d0 + tx4]) = o;
        }
    } else if (t < 576) {
        // H[f][d] = sum_e Uq[e,f] * (Vk[e,d]*gk[d]); A natural [e][f], B natural [e][d] scaled
        const int t2 = t - 512;
        const int ft = t2 & 3, dt = (t2 >> 2) & 3, ks = t2 >> 4;
        const int f0 = ft * 64, d0 = dt * 64, kc = ks * 64;
        float acc[4][4] = {};
        for (int kt = 0; kt < 64; kt += 32) {
            stage_N1(Uq, DA, kc + kt, f0, tid, sA);
            {
                const int k = tid >> 4, n4 = (tid & 15) * 4;
                float4 g = *reinterpret_cast<const float4*>(&gk[d0 + n4]);
                #pragma unroll
                for (int pass = 0; pass < 2; ++pass) {
                    int kk = k + pass * 16;
                    float4 v = *reinterpret_cast<const float4*>(&Vk[(kc + kt + kk) * DA + d0 + n4]);
                    v.x *= g.x; v.y *= g.y; v.z *= g.z; v.w *= g.w;
                    *reinterpret_cast<float4*>(&sB[kk * LDP + n4]) = v;
                }
            }
            __syncthreads();
            mm_inner(sA, sB, tid, acc);
            __syncthreads();
        }
        float* outp = Hp + ks * (DA * DA);
        #pragma unroll
        for (int i = 0; i < 4; ++i) {
            float4 o = make_float4(acc[i][0], acc[i][1], acc[i][2], acc[i][3]);
            *reinterpret_cast<float4*>(&outp[(f0 + ty4 + i) * DA + d0 + tx4]) = o;
        }
    } else if (t == 576) {
        float* w4  = sA;   // [4][256]
        float* tmp = sB;   // [256][4]
        float gkd = gk[tid];
        w4[0 * 256 + tid] = wk[tid] * gkd;
        w4[1 * 256 + tid] = bk[tid] * gkd;
        w4[2 * 256 + tid] = gkd;
        w4[3 * 256 + tid] = bkln[tid];
        __syncthreads();
        const int dl = tid & 15, eg = tid >> 4;
        for (int eb = 0; eb < 16; ++eb) {
            int e = eb * 16 + eg;
            float p0 = 0.f, p1 = 0.f, p2 = 0.f, p3 = 0.f;
            #pragma unroll
            for (int tt = 0; tt < 16; ++tt) {
                int d = dl + tt * 16;
                float v = Vk[e * DA + d];
                p0 = fmaf(v, w4[d], p0);
                p1 = fmaf(v, w4[256 + d], p1);
                p2 = fmaf(v, w4[512 + d], p2);
                p3 = fmaf(v, w4[768 + d], p3);
            }
            #pragma unroll
            for (int m = 8; m > 0; m >>= 1) {
                p0 += __shfl_xor(p0, m, 16);
                p1 += __shfl_xor(p1, m, 16);
                p2 += __shfl_xor(p2, m, 16);
                p3 += __shfl_xor(p3, m, 16);
            }
            if (dl == 0) {
                tmp[e * 4 + 0] = p0; tmp[e * 4 + 1] = p1;
                tmp[e * 4 + 2] = p2; tmp[e * 4 + 3] = p3;
            }
        }
        __syncthreads();
        float a0 = 0.f, a1 = 0.f, a2 = 0.f, a3 = 0.f;
        for (int e = 0; e < 256; ++e) {
            float u = Uq[e * DA + tid];
            a0 = fmaf(u, tmp[e * 4 + 0], a0);
            a1 = fmaf(u, tmp[e * 4 + 1], a1);
            a2 = fmaf(u, tmp[e * 4 + 2], a2);
            a3 = fmaf(u, tmp[e * 4 + 3], a3);
        }
        vec4[tid] = a0; vec4[256 + tid] = a1; vec4[512 + tid] = a2; vec4[768 + tid] = a3;
    } else {
        // per-p LN stats: one wave per p
        const int tp = t - 577;
        const int wid = tid >> 6, lane = tid & 63;
        const int p = tp * 4 + wid;
        const int d4 = lane * 4;
        const float inv = 1.0f / DA;
        float4 ek4 = *reinterpret_cast<const float4*>(&Ek[p * DA + d4]);
        float4 ev4 = *reinterpret_cast<const float4*>(&Ev[p * DA + d4]);
        float4 wk4 = *reinterpret_cast<const float4*>(&wk[d4]);
        float4 bk4 = *reinterpret_cast<const float4*>(&bk[d4]);
        float4 wv4 = *reinterpret_cast<const float4*>(&wv[d4]);
        float4 bv4 = *reinterpret_cast<const float4*>(&bv[d4]);
        float ck0 = bk4.x + ek4.x, ck1 = bk4.y + ek4.y, ck2 = bk4.z + ek4.z, ck3 = bk4.w + ek4.w;
        float cv0 = bv4.x + ev4.x, cv1 = bv4.y + ev4.y, cv2 = bv4.z + ev4.z, cv3 = bv4.w + ev4.w;
        float Sck  = wsum(ck0 + ck1 + ck2 + ck3);
        float Sck2 = wsum(ck0*ck0 + ck1*ck1 + ck2*ck2 + ck3*ck3);
        float Swck = wsum(wk4.x*ck0 + wk4.y*ck1 + wk4.z*ck2 + wk4.w*ck3);
        float Scv  = wsum(cv0 + cv1 + cv2 + cv3);
        float Scv2 = wsum(cv0*cv0 + cv1*cv1 + cv2*cv2 + cv3*cv3);
        float Swcv = wsum(wv4.x*cv0 + wv4.y*cv1 + wv4.z*cv2 + wv4.w*cv3);
        float Swk  = wsum(wk4.x + wk4.y + wk4.z + wk4.w);
        float Swv  = wsum(wv4.x + wv4.y + wv4.z + wv4.w);
        float mwk = Swk * inv, mwv = Swv * inv;
        float mck = Sck * inv, mcv = Scv * inv;
        if (lane == 0) {
            pst[0 * P + p] = mck;
            pst[1 * P + p] = Swck * inv - mwk * mck;
            pst[2 * P + p] = Sck2 * inv - mck * mck;
            pst[3 * P + p] = mcv;
            pst[4 * P + p] = Swcv * inv - mwv * mcv;
            pst[5 * P + p] = Scv2 * inv - mcv * mcv;
        }
        if (p == 0) {
            float Swk2 = wsum(wk4.x*wk4.x + wk4.y*wk4.y + wk4.z*wk4.z + wk4.w*wk4.w);
            float Swv2 = wsum(wv4.x*wv4.x + wv4.y*wv4.y + wv4.z*wv4.z + wv4.w*wv4.w);
            if (lane == 0) {
                scal4[0] = mwk;
                scal4[1] = Swk2 * inv - mwk * mwk;
                scal4[2] = mwv;
                scal4[3] = Swv2 * inv - mwv * mwv;
            }
        }
    }
}

// ---------------------------------------------------------------- KC:
//  t in [0,512)   : LN(sum qp + bq) -> q; 4 scalar dots vs vec4 -> bscal
//  t in [512,768) : Np[ks][f][p] = sum_d H[f,d]*Ek[p,d], KS=4 (chunk 64), H = 4-partial sum
__global__ __launch_bounds__(256) void KC(const float* __restrict__ qp, const float* __restrict__ bq,
                                          const float* __restrict__ gq, const float* __restrict__ bqln,
                                          const float* __restrict__ vec4, const float* __restrict__ Hp,
                                          const float* __restrict__ Ek,
                                          float* __restrict__ qout, float* __restrict__ Np,
                                          float* __restrict__ bscal) {
    __shared__ __align__(16) float sA[32 * LDP];
    __shared__ __align__(16) float sB[32 * LDP];
    __shared__ float red[4];
    const int tid = threadIdx.x;
    const int t = blockIdx.x;

    if (t < 512) {
        const int b = t, d = tid;
        float x = bq[d];
        #pragma unroll
        for (int ks = 0; ks < 16; ++ks) x += qp[ks * BD + b * DA + d];
        float mu = block_reduce_sum(x, red) * (1.0f / DA);
        float xc = x - mu;
        float var = block_reduce_sum(xc * xc, red) * (1.0f / DA);
        float qv = xc * rsqrtf(var + 1e-5f) * gq[d] + bqln[d];
        qout[b * DA + d] = qv;
        float Wg = block_reduce_sum(qv * vec4[d], red);
        float Cg = block_reduce_sum(qv * vec4[256 + d], red);
        float G_ = block_reduce_sum(qv * vec4[512 + d], red);
        float Bb = block_reduce_sum(qv * vec4[768 + d], red);
        if (d == 0) {
            bscal[b] = Wg; bscal[B + b] = Cg;
            bscal[2 * B + b] = G_; bscal[3 * B + b] = Bb;
        }
    } else {
        const int ty4 = (tid >> 4) * 4, tx4 = (tid & 15) * 4;
        const int t2 = t - 512;
        const int ft = t2 & 3, pt = (t2 >> 2) & 15, ks = t2 >> 6;
        const int f0 = ft * 64, p0 = pt * 64, kc = ks * 64;
        float acc[4][4] = {};
        for (int kt = 0; kt < 64; kt += 32) {
            stage_T4(Hp, DA * DA, DA, f0, kc + kt, tid, sA);  // H[f][d] -> sA[d][f], sum 4
            stage_T(Ek, DA, p0, kc + kt, tid, sB);            // Ek[p][d] -> sB[d][p]
            __syncthreads();
            mm_inner(sA, sB, tid, acc);
            __syncthreads();
        }
        float* outp = Np + ks * (DA * P);
        #pragma unroll
        for (int i = 0; i < 4; ++i) {
            float4 o = make_float4(acc[i][0], acc[i][1], acc[i][2], acc[i][3]);
            *reinterpret_cast<float4*>(&outp[(f0 + ty4 + i) * P + p0 + tx4]) = o;
        }
    }
}

// ---------------------------------------------------------------- KD: epart[ks] = q @ N, KS=4 (chunk 64)
__global__ __launch_bounds__(256) void KD(const float* __restrict__ q, const float* __restrict__ Np,
                                          float* __restrict__ epart) {
    __shared__ __align__(16) float sA[32 * LDP];
    __shared__ __align__(16) float sB[32 * LDP];
    const int tid = threadIdx.x, t = blockIdx.x;
    const int ty4 = (tid >> 4) * 4, tx4 = (tid & 15) * 4;
    const int bt = t & 7, pt = (t >> 3) & 15, ks = t >> 7;
    const int b0 = bt * 64, p0 = pt * 64, kc = ks * 64;
    float acc[4][4] = {};
    for (int kt = 0; kt < 64; kt += 32) {
        stage_T(q, DA, b0, kc + kt, tid, sA);                 // q[b][f] -> sA[f][b]
        stage_N4(Np, DA * P, P, kc + kt, p0, tid, sB);        // N[f][p] natural, sum 4
        __syncthreads();
        mm_inner(sA, sB, tid, acc);
        __syncthreads();
    }
    float* outp = epart + ks * BP;
    #pragma unroll
    for (int i = 0; i < 4; ++i) {
        float4 o = make_float4(acc[i][0], acc[i][1], acc[i][2], acc[i][3]);
        *reinterpret_cast<float4*>(&outp[(b0 + ty4 + i) * P + p0 + tx4]) = o;
    }
}

// ---------------------------------------------------------------- KE: per-b epilogue: e->u->alpha, w=u*rstd_v, scalars, out_c base
__global__ __launch_bounds__(256) void KE(const float* __restrict__ epart, const float* __restrict__ desc,
                                          const float* __restrict__ bscal, const float* __restrict__ pst,
                                          const float* __restrict__ scal4,
                                          const float* __restrict__ gv, const float* __restrict__ wv,
                                          const float* __restrict__ bvv, const float* __restrict__ bvln,
                                          float* __restrict__ alpha_out, float* __restrict__ wbuf,
                                          float* __restrict__ bscal2, float* __restrict__ out_c) {
    __shared__ float red[4];
    const int b = blockIdx.x, tid = threadIdx.x;
    const float mwk = scal4[0], Ak = scal4[1], mwv = scal4[2], Av = scal4[3];
    const float Wg = bscal[b], Cg = bscal[B + b], G_ = bscal[2 * B + b], Bb = bscal[3 * B + b];
    float u[4];
    float us = 0.f, ws_ = 0.f, wss = 0.f, wms = 0.f;
    #pragma unroll
    for (int j = 0; j < 4; ++j) {
        int p = j * 256 + tid;
        float dot = epart[b * P + p] + epart[BP + b * P + p]
                  + epart[2 * BP + b * P + p] + epart[3 * BP + b * P + p];
        float s = desc[b * P + p];
        float mck = pst[p], Bk = pst[P + p], Ck = pst[2 * P + p];
        float var = fmaf(s, fmaf(s, Ak, 2.0f * Bk), Ck);
        float rstd = rsqrtf(var + 1e-5f);
        float mu = fmaf(s, mwk, mck);
        float e = (rstd * (fmaf(s, Wg, Cg) + dot - mu * G_) + Bb) * 0.0625f;
        float uu = 1.0f / (1.0f + expf(-e));
        float mcv = pst[3 * P + p], Bv = pst[4 * P + p], Cv = pst[5 * P + p];
        float varv = fmaf(s, fmaf(s, Av, 2.0f * Bv), Cv);
        float rv = rsqrtf(varv + 1e-5f);
        float ww = uu * rv;
        wbuf[b * P + p] = ww;
        u[j] = uu;
        us += uu; ws_ += ww;
        wss = fmaf(ww, s, wss);
        wms = fmaf(ww, fmaf(s, mwv, mcv), wms);
    }
    float S   = block_reduce_sum(us, red);
    float SB  = block_reduce_sum(ws_, red);
    float SBs = block_reduce_sum(wss, red);
    float SBm = block_reduce_sum(wms, red);
    float invS = 1.0f / (S + 1e-12f);
    float T = S * invS;
    #pragma unroll
    for (int j = 0; j < 4; ++j)
        alpha_out[b * P + j * 256 + tid] = u[j] * invS;
    if (tid == 0) bscal2[b] = invS;
    const int d = tid;
    out_c[b * DA + d] = invS * (gv[d] * (wv[d] * SBs + bvv[d] * SB - SBm)) + bvln[d] * T;
}

// ---------------------------------------------------------------- KF: c += gv*invS * (w @ Ev), KS=16 (chunk 64), atomic epilogue
__global__ __launch_bounds__(256) void KF(const float* __restrict__ wbuf, const float* __restrict__ Ev,
                                          const float* __restrict__ bscal2, const float* __restrict__ gv,
                                          float* __restrict__ out_c) {
    __shared__ __align__(16) float sA[32 * LDP];
    __shared__ __align__(16) float sB[32 * LDP];
    const int tid = threadIdx.x, t = blockIdx.x;
    const int ty4 = (tid >> 4) * 4, tx4 = (tid & 15) * 4;
    const int mt = t & 7, nt = (t >> 3) & 3, ks = t >> 5;
    const int b0 = mt * 64, d0 = nt * 64, kc = ks * 64;
    float acc[4][4] = {};
    for (int kt = 0; kt < 64; kt += 32) {
        stage_T(wbuf, P, b0, kc + kt, tid, sA);
        stage_N1(Ev, DA, kc + kt, d0, tid, sB);
        __syncthreads();
        mm_inner(sA, sB, tid, acc);
        __syncthreads();
    }
    float4 g4 = *reinterpret_cast<const float4*>(&gv[d0 + tx4]);
    #pragma unroll
    for (int i = 0; i < 4; ++i) {
        const int b = b0 + ty4 + i;
        const float sc = bscal2[b];
        float* dst = &out_c[b * DA + d0 + tx4];
        atomicAdd(dst + 0, acc[i][0] * sc * g4.x);
        atomicAdd(dst + 1, acc[i][1] * sc * g4.y);
        atomicAdd(dst + 2, acc[i][2] * sc * g4.z);
        atomicAdd(dst + 3, acc[i][3] * sc * g4.w);
    }
}

// ---------------------------------------------------------------- launch
extern "C" void kernel_launch(void* const* d_in, const int* in_sizes, int n_in,
                              void* d_out, int out_size, void* d_ws, size_t ws_size,
                              hipStream_t stream) {
    (void)in_sizes; (void)n_in; (void)out_size; (void)ws_size;
    const float* hg   = (const float*)d_in[0];
    const float* desc = (const float*)d_in[1];
    const float* Wq   = (const float*)d_in[2];
    const float* bq   = (const float*)d_in[3];
    const float* wk   = (const float*)d_in[4];
    const float* bk   = (const float*)d_in[5];
    const float* wv   = (const float*)d_in[6];
    const float* bv   = (const float*)d_in[7];
    const float* Ek   = (const float*)d_in[8];
    const float* Ev   = (const float*)d_in[9];
    const float* Uq   = (const float*)d_in[10];
    const float* Vk   = (const float*)d_in[11];
    const float* gq   = (const float*)d_in[12];
    const float* bqln = (const float*)d_in[13];
    const float* gk   = (const float*)d_in[14];
    const float* bkln = (const float*)d_in[15];
    const float* gv   = (const float*)d_in[16];
    const float* bvln = (const float*)d_in[17];

    float* out = (float*)d_out;
    float* out_c = out;              // B*DA
    float* out_alpha = out + BD;     // B*P

    float* ws = (float*)d_ws;
    float* qp    = ws;               // 16 * BD      = 2097152
    float* Hp    = ws + 2097152;     // 4 * DA*DA    = 262144
    float* Np    = ws + 2359296;     // 4 * DA*P     = 1048576
    float* q     = ws + 3407872;     // BD           = 131072
    float* epart = ws + 3538944;     // 4 * BP       = 2097152
    float* wbuf  = ws + 5636096;     // BP           = 524288
    float* vec4  = ws + 6160384;     // 1024
    float* bscal = ws + 6161408;     // 2048
    float* bscal2= ws + 6163456;     // 512
    float* pst   = ws + 6163968;     // 6144
    float* scal4 = ws + 6170112;     // 4

    KA<<<833, 256, 0, stream>>>(hg, Wq, Uq, Vk, Ek, Ev, wk, bk, wv, bv, gk, bkln,
                                qp, Hp, pst, scal4, vec4);
    KC<<<768, 256, 0, stream>>>(qp, bq, gq, bqln, vec4, Hp, Ek, q, Np, bscal);
    KD<<<512, 256, 0, stream>>>(q, Np, epart);
    KE<<<512, 256, 0, stream>>>(epart, desc, bscal, pst, scal4, gv, wv, bv, bvln,
                                out_alpha, wbuf, bscal2, out_c);
    KF<<<512, 256, 0, stream>>>(wbuf, Ev, bscal2, gv, out_c);
}

// Round 7
// 70.307 us; speedup vs baseline: 1.2215x; 1.2215x over previous
//
#include <hip/hip_runtime.h>
#include <math.h>

#define B 512
#define DG 1024
#define P 1024
#define DA 256
#define LDP 68
#define BP (B * P)
#define BD (B * DA)

// ---------------------------------------------------------------- reductions
__device__ __forceinline__ float block_reduce_sum(float v, volatile float* red) {
    #pragma unroll
    for (int off = 32; off > 0; off >>= 1) v += __shfl_down(v, off, 64);
    const int lane = threadIdx.x & 63, wid = threadIdx.x >> 6;
    __syncthreads();
    if (lane == 0) red[wid] = v;
    __syncthreads();
    return red[0] + red[1] + red[2] + red[3];
}

__device__ __forceinline__ float wsum(float v) {
    #pragma unroll
    for (int m = 32; m > 0; m >>= 1) v += __shfl_xor(v, m, 64);
    return v;
}
// reduce across the 16 lanes of a tx-group (threads sharing ty)
__device__ __forceinline__ float txsum(float v) {
    #pragma unroll
    for (int m = 8; m > 0; m >>= 1) v += __shfl_xor(v, m, 16);
    return v;
}

#define FMA16(a4, b4, acc)                                   \
    acc[0][0] = fmaf(a4.x, b4.x, acc[0][0]);                 \
    acc[0][1] = fmaf(a4.x, b4.y, acc[0][1]);                 \
    acc[0][2] = fmaf(a4.x, b4.z, acc[0][2]);                 \
    acc[0][3] = fmaf(a4.x, b4.w, acc[0][3]);                 \
    acc[1][0] = fmaf(a4.y, b4.x, acc[1][0]);                 \
    acc[1][1] = fmaf(a4.y, b4.y, acc[1][1]);                 \
    acc[1][2] = fmaf(a4.y, b4.z, acc[1][2]);                 \
    acc[1][3] = fmaf(a4.y, b4.w, acc[1][3]);                 \
    acc[2][0] = fmaf(a4.z, b4.x, acc[2][0]);                 \
    acc[2][1] = fmaf(a4.z, b4.y, acc[2][1]);                 \
    acc[2][2] = fmaf(a4.z, b4.z, acc[2][2]);                 \
    acc[2][3] = fmaf(a4.z, b4.w, acc[2][3]);                 \
    acc[3][0] = fmaf(a4.w, b4.x, acc[3][0]);                 \
    acc[3][1] = fmaf(a4.w, b4.y, acc[3][1]);                 \
    acc[3][2] = fmaf(a4.w, b4.z, acc[3][2]);                 \
    acc[3][3] = fmaf(a4.w, b4.w, acc[3][3]);

#define FMA8(a0, a1, b4, acc)                                \
    acc[0][0] = fmaf(a0, b4.x, acc[0][0]);                   \
    acc[0][1] = fmaf(a0, b4.y, acc[0][1]);                   \
    acc[0][2] = fmaf(a0, b4.z, acc[0][2]);                   \
    acc[0][3] = fmaf(a0, b4.w, acc[0][3]);                   \
    acc[1][0] = fmaf(a1, b4.x, acc[1][0]);                   \
    acc[1][1] = fmaf(a1, b4.y, acc[1][1]);                   \
    acc[1][2] = fmaf(a1, b4.z, acc[1][2]);                   \
    acc[1][3] = fmaf(a1, b4.w, acc[1][3]);

// ---------------------------------------------------------------- staging helpers
// transpose-stage: src [M][ldk] row-major, 64 rows at m0, 32 cols at k0 -> sD[k][m]
__device__ __forceinline__ void stage_T(const float* __restrict__ src, int ldk, int m0, int k0,
                                        int tid, float* sD) {
    const int m = tid >> 3, k4 = (tid & 7) * 4;
    #pragma unroll
    for (int pass = 0; pass < 2; ++pass) {
        int mm = m + pass * 32;
        float4 v = *reinterpret_cast<const float4*>(&src[(m0 + mm) * ldk + k0 + k4]);
        sD[(k4 + 0) * LDP + mm] = v.x; sD[(k4 + 1) * LDP + mm] = v.y;
        sD[(k4 + 2) * LDP + mm] = v.z; sD[(k4 + 3) * LDP + mm] = v.w;
    }
}
// transpose-stage 32 rows at m0, 32 cols at k0 -> sD[k][m]
__device__ __forceinline__ void stage_T32(const float* __restrict__ src, int ldk, int m0, int k0,
                                          int tid, float* sD) {
    const int m = tid >> 3, k4 = (tid & 7) * 4;
    float4 v = *reinterpret_cast<const float4*>(&src[(m0 + m) * ldk + k0 + k4]);
    sD[(k4 + 0) * LDP + m] = v.x; sD[(k4 + 1) * LDP + m] = v.y;
    sD[(k4 + 2) * LDP + m] = v.z; sD[(k4 + 3) * LDP + m] = v.w;
}
// natural-stage: src [K][ldn], 32 rows at k0, 64 cols at n0 -> sD[k][n]
__device__ __forceinline__ void stage_N1(const float* __restrict__ src, int ldn, int k0, int n0,
                                         int tid, float* sD) {
    const int k = tid >> 4, n4 = (tid & 15) * 4;
    #pragma unroll
    for (int pass = 0; pass < 2; ++pass) {
        int kk = k + pass * 16;
        *reinterpret_cast<float4*>(&sD[kk * LDP + n4]) =
            *reinterpret_cast<const float4*>(&src[(k0 + kk) * ldn + n0 + n4]);
    }
}
// natural-stage summing 4 split-K partials spaced pstride apart
__device__ __forceinline__ void stage_N4(const float* __restrict__ src, int pstride, int ldn,
                                         int k0, int n0, int tid, float* sD) {
    const int k = tid >> 4, n4 = (tid & 15) * 4;
    #pragma unroll
    for (int pass = 0; pass < 2; ++pass) {
        int kk = k + pass * 16;
        const float* base = &src[(k0 + kk) * ldn + n0 + n4];
        float4 v = *reinterpret_cast<const float4*>(base);
        #pragma unroll
        for (int s = 1; s < 4; ++s) {
            float4 w = *reinterpret_cast<const float4*>(base + s * pstride);
            v.x += w.x; v.y += w.y; v.z += w.z; v.w += w.w;
        }
        *reinterpret_cast<float4*>(&sD[kk * LDP + n4]) = v;
    }
}
__device__ __forceinline__ void mm_inner(const float* sA, const float* sB, int tid, float acc[4][4]) {
    const int ty4 = (tid >> 4) * 4, tx4 = (tid & 15) * 4;
    #pragma unroll
    for (int kk = 0; kk < 32; ++kk) {
        float4 a4 = *reinterpret_cast<const float4*>(&sA[kk * LDP + ty4]);
        float4 b4 = *reinterpret_cast<const float4*>(&sB[kk * LDP + tx4]);
        FMA16(a4, b4, acc)
    }
}

// ---------------------------------------------------------------- KA:
//  t in [0,256)    : k1 - qp[ks] = hg@Wq^T partial, 64x64 tile, KS=8 (chunk 128)
//  t in [256,512)  : G  - Gp[ks][e][p] = sum_d Vk[e,d]*gk[d]*Ek[p,d], 64x64, KS=4 (chunk 64)
//  t in [512,576)  : UqT transpose
//  t == 576        : vec4 chained matvecs + zero Sacc
//  t in [577,833)  : per-p LN stats, one wave per p
__global__ __launch_bounds__(256) void KA(const float* __restrict__ hg, const float* __restrict__ Wq,
                                          const float* __restrict__ Uq, const float* __restrict__ Vk,
                                          const float* __restrict__ Ek, const float* __restrict__ Ev,
                                          const float* __restrict__ wk, const float* __restrict__ bk,
                                          const float* __restrict__ wv, const float* __restrict__ bv,
                                          const float* __restrict__ gk, const float* __restrict__ bkln,
                                          float* __restrict__ qp, float* __restrict__ Gp,
                                          float* __restrict__ UqT, float* __restrict__ Sacc,
                                          float* __restrict__ pst, float* __restrict__ scal4,
                                          float* __restrict__ vec4) {
    __shared__ __align__(16) float sA[32 * LDP];
    __shared__ __align__(16) float sB[32 * LDP];
    const int tid = threadIdx.x;
    const int t = blockIdx.x;
    const int ty4 = (tid >> 4) * 4, tx4 = (tid & 15) * 4;

    if (t < 256) {
        const int mt = t & 7, nt = (t >> 3) & 3, ks = t >> 5;
        const int b0 = mt * 64, d0 = nt * 64, kc = ks * 128;
        float acc[4][4] = {};
        for (int kt = 0; kt < 128; kt += 32) {
            stage_T(hg, DG, b0, kc + kt, tid, sA);
            stage_T(Wq, DG, d0, kc + kt, tid, sB);
            __syncthreads();
            mm_inner(sA, sB, tid, acc);
            __syncthreads();
        }
        float* outp = qp + ks * BD;
        #pragma unroll
        for (int i = 0; i < 4; ++i) {
            float4 o = make_float4(acc[i][0], acc[i][1], acc[i][2], acc[i][3]);
            *reinterpret_cast<float4*>(&outp[(b0 + ty4 + i) * DA + d0 + tx4]) = o;
        }
    } else if (t < 512) {
        // G[e][p] = sum_d (Vk[e,d]*gk[d]) * Ek[p,d]
        const int t2 = t - 256;
        const int et = t2 & 3, pt = (t2 >> 2) & 15, ks = t2 >> 6;
        const int e0 = et * 64, p0 = pt * 64, kc = ks * 64;
        float acc[4][4] = {};
        for (int kt = 0; kt < 64; kt += 32) {
            const int kg = kc + kt;
            {   // A: Vk rows e0..e0+63, cols kg..kg+31, scaled by gk -> sA[d][e]
                const int m = tid >> 3, k4 = (tid & 7) * 4;
                float4 g = *reinterpret_cast<const float4*>(&gk[kg + k4]);
                #pragma unroll
                for (int pass = 0; pass < 2; ++pass) {
                    int mm = m + pass * 32;
                    float4 v = *reinterpret_cast<const float4*>(&Vk[(e0 + mm) * DA + kg + k4]);
                    sA[(k4 + 0) * LDP + mm] = v.x * g.x; sA[(k4 + 1) * LDP + mm] = v.y * g.y;
                    sA[(k4 + 2) * LDP + mm] = v.z * g.z; sA[(k4 + 3) * LDP + mm] = v.w * g.w;
                }
            }
            stage_T(Ek, DA, p0, kg, tid, sB);
            __syncthreads();
            mm_inner(sA, sB, tid, acc);
            __syncthreads();
        }
        float* outp = Gp + ks * (DA * P);
        #pragma unroll
        for (int i = 0; i < 4; ++i) {
            float4 o = make_float4(acc[i][0], acc[i][1], acc[i][2], acc[i][3]);
            *reinterpret_cast<float4*>(&outp[(e0 + ty4 + i) * P + p0 + tx4]) = o;
        }
    } else if (t < 576) {
        const int b2 = t - 512;
        const int e0 = (b2 & 7) * 32, f0 = (b2 >> 3) * 32;
        const int col = tid & 31, row8 = tid >> 5;
        #pragma unroll
        for (int pass = 0; pass < 4; ++pass) {
            int r = row8 + pass * 8;
            sA[r * 33 + col] = Uq[(e0 + r) * DA + f0 + col];
        }
        __syncthreads();
        #pragma unroll
        for (int pass = 0; pass < 4; ++pass) {
            int r = row8 + pass * 8;
            UqT[(f0 + r) * DA + e0 + col] = sA[col * 33 + r];
        }
    } else if (t == 576) {
        // zero the atomic scalar accumulators (4 x B)
        #pragma unroll
        for (int j = 0; j < 8; ++j) Sacc[j * 256 + tid] = 0.f;
        // vec4[j][f] = sum_e Uq[e,f] * (sum_d Vk[e,d]*w4[j][d])
        float* w4  = sA;   // [4][256]
        float* tmp = sB;   // [256][4]
        float gkd = gk[tid];
        w4[0 * 256 + tid] = wk[tid] * gkd;
        w4[1 * 256 + tid] = bk[tid] * gkd;
        w4[2 * 256 + tid] = gkd;
        w4[3 * 256 + tid] = bkln[tid];
        __syncthreads();
        const int dl = tid & 15, eg = tid >> 4;
        for (int eb = 0; eb < 16; ++eb) {
            int e = eb * 16 + eg;
            float p0 = 0.f, p1 = 0.f, p2 = 0.f, p3 = 0.f;
            #pragma unroll
            for (int tt = 0; tt < 16; ++tt) {
                int d = dl + tt * 16;
                float v = Vk[e * DA + d];
                p0 = fmaf(v, w4[d], p0);
                p1 = fmaf(v, w4[256 + d], p1);
                p2 = fmaf(v, w4[512 + d], p2);
                p3 = fmaf(v, w4[768 + d], p3);
            }
            #pragma unroll
            for (int m = 8; m > 0; m >>= 1) {
                p0 += __shfl_xor(p0, m, 16);
                p1 += __shfl_xor(p1, m, 16);
                p2 += __shfl_xor(p2, m, 16);
                p3 += __shfl_xor(p3, m, 16);
            }
            if (dl == 0) {
                tmp[e * 4 + 0] = p0; tmp[e * 4 + 1] = p1;
                tmp[e * 4 + 2] = p2; tmp[e * 4 + 3] = p3;
            }
        }
        __syncthreads();
        float a0 = 0.f, a1 = 0.f, a2 = 0.f, a3 = 0.f;
        for (int e = 0; e < 256; ++e) {
            float u = Uq[e * DA + tid];
            a0 = fmaf(u, tmp[e * 4 + 0], a0);
            a1 = fmaf(u, tmp[e * 4 + 1], a1);
            a2 = fmaf(u, tmp[e * 4 + 2], a2);
            a3 = fmaf(u, tmp[e * 4 + 3], a3);
        }
        vec4[tid] = a0; vec4[256 + tid] = a1; vec4[512 + tid] = a2; vec4[768 + tid] = a3;
    } else {
        // per-p LN stats: one wave per p
        const int tp = t - 577;
        const int wid = tid >> 6, lane = tid & 63;
        const int p = tp * 4 + wid;
        const int d4 = lane * 4;
        const float inv = 1.0f / DA;
        float4 ek4 = *reinterpret_cast<const float4*>(&Ek[p * DA + d4]);
        float4 ev4 = *reinterpret_cast<const float4*>(&Ev[p * DA + d4]);
        float4 wk4 = *reinterpret_cast<const float4*>(&wk[d4]);
        float4 bk4 = *reinterpret_cast<const float4*>(&bk[d4]);
        float4 wv4 = *reinterpret_cast<const float4*>(&wv[d4]);
        float4 bv4 = *reinterpret_cast<const float4*>(&bv[d4]);
        float ck0 = bk4.x + ek4.x, ck1 = bk4.y + ek4.y, ck2 = bk4.z + ek4.z, ck3 = bk4.w + ek4.w;
        float cv0 = bv4.x + ev4.x, cv1 = bv4.y + ev4.y, cv2 = bv4.z + ev4.z, cv3 = bv4.w + ev4.w;
        float Sck  = wsum(ck0 + ck1 + ck2 + ck3);
        float Sck2 = wsum(ck0*ck0 + ck1*ck1 + ck2*ck2 + ck3*ck3);
        float Swck = wsum(wk4.x*ck0 + wk4.y*ck1 + wk4.z*ck2 + wk4.w*ck3);
        float Scv  = wsum(cv0 + cv1 + cv2 + cv3);
        float Scv2 = wsum(cv0*cv0 + cv1*cv1 + cv2*cv2 + cv3*cv3);
        float Swcv = wsum(wv4.x*cv0 + wv4.y*cv1 + wv4.z*cv2 + wv4.w*cv3);
        float Swk  = wsum(wk4.x + wk4.y + wk4.z + wk4.w);
        float Swv  = wsum(wv4.x + wv4.y + wv4.z + wv4.w);
        float mwk = Swk * inv, mwv = Swv * inv;
        float mck = Sck * inv, mcv = Scv * inv;
        if (lane == 0) {
            pst[0 * P + p] = mck;
            pst[1 * P + p] = Swck * inv - mwk * mck;
            pst[2 * P + p] = Sck2 * inv - mck * mck;
            pst[3 * P + p] = mcv;
            pst[4 * P + p] = Swcv * inv - mwv * mcv;
            pst[5 * P + p] = Scv2 * inv - mcv * mcv;
        }
        if (p == 0) {
            float Swk2 = wsum(wk4.x*wk4.x + wk4.y*wk4.y + wk4.z*wk4.z + wk4.w*wk4.w);
            float Swv2 = wsum(wv4.x*wv4.x + wv4.y*wv4.y + wv4.z*wv4.z + wv4.w*wv4.w);
            if (lane == 0) {
                scal4[0] = mwk;
                scal4[1] = Swk2 * inv - mwk * mwk;
                scal4[2] = mwv;
                scal4[3] = Swv2 * inv - mwv * mwv;
            }
        }
    }
}

// ---------------------------------------------------------------- KC: per-b LN -> q; bscal dots; q2 = q @ Uq^T (coalesced via UqT)
__global__ __launch_bounds__(256) void KC(const float* __restrict__ qp, const float* __restrict__ bq,
                                          const float* __restrict__ gq, const float* __restrict__ bqln,
                                          const float* __restrict__ vec4, const float* __restrict__ UqT,
                                          float* __restrict__ q2out, float* __restrict__ bscal) {
    __shared__ __align__(16) float q_lds[DA];
    __shared__ float red[4];
    const int b = blockIdx.x, d = threadIdx.x;
    float x = bq[d];
    #pragma unroll
    for (int ks = 0; ks < 8; ++ks) x += qp[ks * BD + b * DA + d];
    float mu = block_reduce_sum(x, red) * (1.0f / DA);
    float xc = x - mu;
    float var = block_reduce_sum(xc * xc, red) * (1.0f / DA);
    float qv = xc * rsqrtf(var + 1e-5f) * gq[d] + bqln[d];
    q_lds[d] = qv;
    float Wg = block_reduce_sum(qv * vec4[d], red);        // also syncs q_lds
    float Cg = block_reduce_sum(qv * vec4[256 + d], red);
    float G_ = block_reduce_sum(qv * vec4[512 + d], red);
    float Bb = block_reduce_sum(qv * vec4[768 + d], red);
    if (d == 0) {
        bscal[b] = Wg; bscal[B + b] = Cg;
        bscal[2 * B + b] = G_; bscal[3 * B + b] = Bb;
    }
    float q2 = 0.f;
    for (int f = 0; f < DA; f += 4) {
        float4 qf = *reinterpret_cast<const float4*>(&q_lds[f]);
        q2 = fmaf(qf.x, UqT[(f + 0) * DA + d], q2);
        q2 = fmaf(qf.y, UqT[(f + 1) * DA + d], q2);
        q2 = fmaf(qf.z, UqT[(f + 2) * DA + d], q2);
        q2 = fmaf(qf.w, UqT[(f + 3) * DA + d], q2);
    }
    q2out[b * DA + d] = q2;
}

// ---------------------------------------------------------------- KD: e = q2 @ G (full K=256, 32x64 tile) + fused epilogue
// writes ubuf, wbuf; atomically accumulates Sacc[{S,SB,SBs,SBm}][b]
__global__ __launch_bounds__(256) void KD(const float* __restrict__ q2, const float* __restrict__ Gp,
                                          const float* __restrict__ desc, const float* __restrict__ bscal,
                                          const float* __restrict__ pst, const float* __restrict__ scal4,
                                          float* __restrict__ ubuf, float* __restrict__ wbuf,
                                          float* __restrict__ Sacc) {
    __shared__ __align__(16) float sA[32 * LDP];
    __shared__ __align__(16) float sB[32 * LDP];
    const int tid = threadIdx.x, t = blockIdx.x;
    const int tx = tid & 15, ty = tid >> 4;
    const int tx4 = tx * 4;
    const int b0 = (t & 15) * 32, p0 = (t >> 4) * 64;
    float acc[2][4] = {};
    for (int kt = 0; kt < 256; kt += 32) {
        stage_T32(q2, DA, b0, kt, tid, sA);               // q2[b][e] -> sA[e][b]
        stage_N4(Gp, DA * P, P, kt, p0, tid, sB);         // G[e][p] natural, sum 4 partials
        __syncthreads();
        #pragma unroll
        for (int kk = 0; kk < 32; ++kk) {
            float a0 = sA[kk * LDP + ty * 2 + 0];
            float a1 = sA[kk * LDP + ty * 2 + 1];
            float4 b4 = *reinterpret_cast<const float4*>(&sB[kk * LDP + tx4]);
            FMA8(a0, a1, b4, acc)
        }
        __syncthreads();
    }
    const float mwk = scal4[0], Ak = scal4[1], mwv = scal4[2], Av = scal4[3];
    #pragma unroll
    for (int i = 0; i < 2; ++i) {
        const int b = b0 + ty * 2 + i;
        const float Wg = bscal[b], Cg = bscal[B + b], G_ = bscal[2 * B + b], Bb = bscal[3 * B + b];
        float4 uo, wo;
        float* up = &uo.x; float* wp = &wo.x;
        float us = 0.f, ws_ = 0.f, wss = 0.f, wms = 0.f;
        #pragma unroll
        for (int j = 0; j < 4; ++j) {
            const int p = p0 + tx4 + j;
            float s = desc[b * P + p];
            float mck = pst[p], Bk = pst[P + p], Ck = pst[2 * P + p];
            float var = fmaf(s, fmaf(s, Ak, 2.0f * Bk), Ck);
            float rstd = rsqrtf(var + 1e-5f);
            float mu = fmaf(s, mwk, mck);
            float e = (rstd * (fmaf(s, Wg, Cg) + acc[i][j] - mu * G_) + Bb) * 0.0625f;
            float uu = 1.0f / (1.0f + expf(-e));
            float mcv = pst[3 * P + p], Bv = pst[4 * P + p], Cv = pst[5 * P + p];
            float varv = fmaf(s, fmaf(s, Av, 2.0f * Bv), Cv);
            float rv = rsqrtf(varv + 1e-5f);
            float ww = uu * rv;
            up[j] = uu; wp[j] = ww;
            us += uu; ws_ += ww;
            wss = fmaf(ww, s, wss);
            wms = fmaf(ww, fmaf(s, mwv, mcv), wms);
        }
        *reinterpret_cast<float4*>(&ubuf[b * P + p0 + tx4]) = uo;
        *reinterpret_cast<float4*>(&wbuf[b * P + p0 + tx4]) = wo;
        us = txsum(us); ws_ = txsum(ws_); wss = txsum(wss); wms = txsum(wms);
        if (tx == 0) {
            atomicAdd(&Sacc[b], us);
            atomicAdd(&Sacc[B + b], ws_);
            atomicAdd(&Sacc[2 * B + b], wss);
            atomicAdd(&Sacc[3 * B + b], wms);
        }
    }
}

// ---------------------------------------------------------------- KF: cpart[ks] = wbuf @ Ev partial (64x64 tile, chunk 128, KS=8)
__global__ __launch_bounds__(256) void KF(const float* __restrict__ wbuf, const float* __restrict__ Ev,
                                          float* __restrict__ cpart) {
    __shared__ __align__(16) float sA[32 * LDP];
    __shared__ __align__(16) float sB[32 * LDP];
    const int tid = threadIdx.x, t = blockIdx.x;
    const int ty4 = (tid >> 4) * 4, tx4 = (tid & 15) * 4;
    const int mt = t & 7, nt = (t >> 3) & 3, ks = t >> 5;
    const int b0 = mt * 64, d0 = nt * 64, kc = ks * 128;
    float acc[4][4] = {};
    for (int kt = 0; kt < 128; kt += 32) {
        stage_T(wbuf, P, b0, kc + kt, tid, sA);
        stage_N1(Ev, DA, kc + kt, d0, tid, sB);
        __syncthreads();
        mm_inner(sA, sB, tid, acc);
        __syncthreads();
    }
    float* outp = cpart + ks * BD;
    #pragma unroll
    for (int i = 0; i < 4; ++i) {
        float4 o = make_float4(acc[i][0], acc[i][1], acc[i][2], acc[i][3]);
        *reinterpret_cast<float4*>(&outp[(b0 + ty4 + i) * DA + d0 + tx4]) = o;
    }
}

// ---------------------------------------------------------------- KG: per-b: alpha = u*invS, c final
__global__ __launch_bounds__(256) void KG(const float* __restrict__ cpart, const float* __restrict__ Sacc,
                                          const float* __restrict__ ubuf,
                                          const float* __restrict__ gv, const float* __restrict__ wv,
                                          const float* __restrict__ bvv, const float* __restrict__ bvln,
                                          float* __restrict__ alpha_out, float* __restrict__ out_c) {
    const int b = blockIdx.x, tid = threadIdx.x;
    const float S = Sacc[b], SB = Sacc[B + b], SBs = Sacc[2 * B + b], SBm = Sacc[3 * B + b];
    const float invS = 1.0f / (S + 1e-12f);
    const float T = S * invS;
    #pragma unroll
    for (int j = 0; j < 4; ++j) {
        int p = j * 256 + tid;
        alpha_out[b * P + p] = ubuf[b * P + p] * invS;
    }
    const int d = tid;
    float csum = 0.f;
    #pragma unroll
    for (int ks = 0; ks < 8; ++ks) csum += cpart[ks * BD + b * DA + d];
    out_c[b * DA + d] =
        invS * (gv[d] * (wv[d] * SBs + bvv[d] * SB + csum - SBm)) + bvln[d] * T;
}

// ---------------------------------------------------------------- launch
extern "C" void kernel_launch(void* const* d_in, const int* in_sizes, int n_in,
                              void* d_out, int out_size, void* d_ws, size_t ws_size,
                              hipStream_t stream) {
    (void)in_sizes; (void)n_in; (void)out_size; (void)ws_size;
    const float* hg   = (const float*)d_in[0];
    const float* desc = (const float*)d_in[1];
    const float* Wq   = (const float*)d_in[2];
    const float* bq   = (const float*)d_in[3];
    const float* wk   = (const float*)d_in[4];
    const float* bk   = (const float*)d_in[5];
    const float* wv   = (const float*)d_in[6];
    const float* bv   = (const float*)d_in[7];
    const float* Ek   = (const float*)d_in[8];
    const float* Ev   = (const float*)d_in[9];
    const float* Uq   = (const float*)d_in[10];
    const float* Vk   = (const float*)d_in[11];
    const float* gq   = (const float*)d_in[12];
    const float* bqln = (const float*)d_in[13];
    const float* gk   = (const float*)d_in[14];
    const float* bkln = (const float*)d_in[15];
    const float* gv   = (const float*)d_in[16];
    const float* bvln = (const float*)d_in[17];

    float* out = (float*)d_out;
    float* out_c = out;              // B*DA
    float* out_alpha = out + BD;     // B*P

    float* ws = (float*)d_ws;
    float* qp    = ws;               // 8 * BD   = 1048576
    float* Gp    = ws + 1048576;     // 4 * DA*P = 1048576
    float* UqT   = ws + 2097152;     // 65536
    float* q2    = ws + 2162688;     // 131072
    float* ubuf  = ws + 2293760;     // 524288
    float* wbuf  = ws + 2818048;     // 524288
    float* cpart = ws + 3342336;     // 8 * BD   = 1048576
    float* vec4  = ws + 4390912;     // 1024
    float* bscal = ws + 4391936;     // 2048
    float* Sacc  = ws + 4393984;     // 2048
    float* pst   = ws + 4396032;     // 6144
    float* scal4 = ws + 4402176;     // 4

    KA<<<833, 256, 0, stream>>>(hg, Wq, Uq, Vk, Ek, Ev, wk, bk, wv, bv, gk, bkln,
                                qp, Gp, UqT, Sacc, pst, scal4, vec4);
    KC<<<512, 256, 0, stream>>>(qp, bq, gq, bqln, vec4, UqT, q2, bscal);
    KD<<<256, 256, 0, stream>>>(q2, Gp, desc, bscal, pst, scal4, ubuf, wbuf, Sacc);
    KF<<<256, 256, 0, stream>>>(wbuf, Ev, cpart);
    KG<<<512, 256, 0, stream>>>(cpart, Sacc, ubuf, gv, wv, bv, bvln, out_alpha, out_c);
}